// Round 12
// baseline (841.733 us; speedup 1.0000x reference)
//
#include <hip/hip_runtime.h>
#include <math.h>

#define B_ 4
#define L_ 2048
#define D_ 1024
#define H_ 16
#define HD_ 64
#define K_ 24
#define MLP_ 4096

typedef unsigned short u16;
typedef short s16x8 __attribute__((ext_vector_type(8)));
typedef float fx4 __attribute__((ext_vector_type(4)));
typedef _Float16 h2 __attribute__((ext_vector_type(2)));

__device__ __forceinline__ u16 f2bf(float f) {
    unsigned u = __float_as_uint(f);
    unsigned r = (u + 0x7fff + ((u >> 16) & 1)) >> 16;
    return (u16)r;
}

__device__ __forceinline__ u16 f2h(float f) {
    _Float16 hv = (_Float16)f;
    return __builtin_bit_cast(u16, hv);
}

__device__ __forceinline__ float gelu_t(float x) {
    float u = 0.7978845608028654f * (x + 0.044715f * x * x * x);
    return x / (1.f + __expf(-2.f * u));
}

__device__ __forceinline__ float exp2_hw(float x) {
    float r;
    asm("v_exp_f32 %0, %1" : "=v"(r) : "v"(x));
    return r;
}

__device__ __forceinline__ void gload_lds16(const void* g, void* l) {
    __builtin_amdgcn_global_load_lds(
        (const __attribute__((address_space(1))) unsigned int*)g,
        (__attribute__((address_space(3))) unsigned int*)l, 16, 0, 0);
}

#define SBAR() do { __builtin_amdgcn_sched_barrier(0); \
                    __builtin_amdgcn_s_barrier(); \
                    __builtin_amdgcn_sched_barrier(0); } while (0)

// ---------------------------------------------------------------------------
// Spectral filters, computed directly transposed+reversed:
// FvT[d][l0 + (l&63)^63] = sum_k eig_vecs[l,k]*ev^0.25[k]*w_filters[k,d] (f16)
// ---------------------------------------------------------------------------
__global__ __launch_bounds__(256) void filters_T(const float* __restrict__ eig_vals,
                                                 const float* __restrict__ eig_vecs,
                                                 const float* __restrict__ w_filters,
                                                 u16* __restrict__ outT) {
    int l0 = blockIdx.x * 64, d0 = blockIdx.y * 64;
    __shared__ float ev25[K_];
    __shared__ float rr[64][25];
    __shared__ float wfs[K_][64];
    int tid = threadIdx.x;
    if (tid < K_) ev25[tid] = powf(eig_vals[tid], 0.25f);
    __syncthreads();
    for (int i = tid; i < 64 * K_; i += 256)
        rr[i / K_][i % K_] = eig_vecs[l0 * K_ + i];
    for (int i = tid; i < K_ * 64; i += 256) {
        int k = i >> 6, dd = i & 63;
        wfs[k][dd] = ev25[k] * w_filters[k * D_ + d0 + dd];
    }
    __syncthreads();
    int lane = tid & 63, w = tid >> 6;
    float acc[16];
#pragma unroll
    for (int i = 0; i < 16; i++) acc[i] = 0.f;
#pragma unroll
    for (int k = 0; k < K_; k++) {
        float rv = rr[lane][k];
#pragma unroll
        for (int i = 0; i < 16; i++) acc[i] += rv * wfs[k][w * 16 + i];
    }
#pragma unroll
    for (int i = 0; i < 16; i++)
        outT[(size_t)(d0 + w * 16 + i) * L_ + l0 + (lane ^ 63)] = f2h(acc[i]);
}

// ---------------------------------------------------------------------------
__global__ __launch_bounds__(256) void cast_bf16(const float* __restrict__ in,
                                                 u16* __restrict__ out) {
    int i = blockIdx.x * 256 + threadIdx.x;
    float4 v = ((const float4*)in)[i];
    ushort4 o;
    o.x = f2bf(v.x); o.y = f2bf(v.y); o.z = f2bf(v.z); o.w = f2bf(v.w);
    ((ushort4*)out)[i] = o;
}

// ---------------------------------------------------------------------------
// Batched fp32 [R][C] -> bf16 [C][R] transpose-cast: all weight transposes
// in ONE launch (job table by value; prefix-offset block mapping).
// ---------------------------------------------------------------------------
struct CastJobs {
    const float* src[8];
    u16* dst[8];
    int R[8], C[8];
    int off[8];   // block prefix offsets; off[j]..off[j+1) -> job j
};

__global__ __launch_bounds__(256) void cast_T_all(CastJobs J) {
    __shared__ float t[32][33];
    int bid = blockIdx.x;
    int j = 0;
#pragma unroll
    for (int k = 1; k < 8; k++)
        if (bid >= J.off[k]) j = k;
    int local = bid - J.off[j];
    int R = J.R[j], C = J.C[j];
    int nbx = C >> 5;                 // power of two (32 or 128)
    int lsh = __ffs(nbx) - 1;
    int bx = local & (nbx - 1), by = local >> lsh;
    const float* in = J.src[j];
    u16* out = J.dst[j];
    int c0 = bx * 32, r0 = by * 32;
    int tx = threadIdx.x & 31, ty = threadIdx.x >> 5;
#pragma unroll
    for (int p = 0; p < 4; p++)
        t[ty + p * 8][tx] = in[(size_t)(r0 + ty + p * 8) * C + c0 + tx];
    __syncthreads();
#pragma unroll
    for (int p = 0; p < 4; p++)
        out[(size_t)(c0 + ty + p * 8) * R + r0 + tx] = f2bf(t[tx][ty + p * 8]);
}

// ---------------------------------------------------------------------------
// bf16 MFMA GEMM, 8-phase schedule (T2+T3+T4+T5). Tile 128x256, BK=64,
// 512 threads = 8 waves, 3-slot LDS rotation, counted vmcnt(6), st_16x32
// swizzle (linear LDS dest + inv-swizzled global src + swizzled ds_read).
// 4 barriers/K-tile (the 3-barrier variant measured slower: wave drift
// grows the lgkmcnt stall at 1 block/CU lockstep).
// qcols: columns < qcols get alpha*0.125*log2(e) -- the Q prescale with
// log2e folded in so attention can use raw v_exp_f32 (base-2).
// f16out: write f16 TRANSPOSED [N][M] via post-loop LDS transpose (XIT path;
//         requires vmcnt(0) drain -- in-flight global_load_lds target lds!).
// ---------------------------------------------------------------------------
__global__ __launch_bounds__(512, 2) void gemm_bf16(
    const u16* __restrict__ A, const u16* __restrict__ Bt,
    float* __restrict__ C, u16* __restrict__ Cb,
    int M, int N, int K, float alpha,
    const float* __restrict__ bias, const float* __restrict__ resid, int act,
    int qcols, int f16out) {
    __shared__ __align__(16) u16 lds[3 * 24576];   // 3 slots x 48KB
    const int SLOT = 24576;   // u16 per slot
    const int BOFF = 8192;    // B-tile offset within slot (u16)

    int tid = threadIdx.x;
    int wid = tid >> 6, lane = tid & 63;
    int quad = lane >> 4, l15 = lane & 15;
    int rb = wid >> 2, cb = wid & 3;

    int bxs = blockIdx.x, bys = blockIdx.y;
    if ((gridDim.y & 7) == 0) {
        int bid = blockIdx.x + gridDim.x * blockIdx.y;
        int xcd = bid & 7, idx = bid >> 3;
        bys = xcd + 8 * (idx / gridDim.x);
        bxs = idx % gridDim.x;
    }
    int bm = bys * 128, bn = bxs * 256;
    int nt = K >> 6;

    int qoffe = (quad * 8) ^ ((l15 & 4) ? 16 : 0);
    int aRd = (rb * 64 + l15) * 64 + qoffe;            // + mf*1024 + kk*32
    int bRd = BOFF + (cb * 64 + l15) * 64 + qoffe;     // + nf*1024 + kk*32

    int srow = wid * 8 + (lane >> 3);
    int scole = ((lane & 7) * 8) ^ ((lane & 32) ? 16 : 0);
    const u16* Ag = A + (size_t)(bm + srow) * K + scole;
    const u16* Bg = Bt + (size_t)(bn + srow) * K + scole;
    int ldst = wid * 512;

#define STAGE_A(s, t, c) gload_lds16(Ag + (size_t)(c) * 64 * K + (size_t)(t) * 64, \
                                     &lds[(s) * SLOT + (c) * 4096 + ldst])
#define STAGE_B(s, t, c) gload_lds16(Bg + (size_t)(c) * 64 * K + (size_t)(t) * 64, \
                                     &lds[(s) * SLOT + BOFF + (c) * 4096 + ldst])

    STAGE_A(0, 0, 0); STAGE_A(0, 0, 1);
    STAGE_B(0, 0, 0); STAGE_B(0, 0, 1); STAGE_B(0, 0, 2); STAGE_B(0, 0, 3);
    STAGE_A(1, 1, 0); STAGE_A(1, 1, 1);
    STAGE_B(1, 1, 0); STAGE_B(1, 1, 1); STAGE_B(1, 1, 2); STAGE_B(1, 1, 3);
    asm volatile("s_waitcnt vmcnt(6)" ::: "memory");
    SBAR();

    fx4 acc[4][4];
#pragma unroll
    for (int i = 0; i < 4; i++)
#pragma unroll
        for (int j = 0; j < 4; j++) acc[i][j] = (fx4){0.f, 0.f, 0.f, 0.f};

    int sa = 0, sb = 1, sc = 2;
    for (int t = 0; t < nt; t++) {
        int ts = (t + 2 < nt) ? t + 2 : nt - 1;
        const u16* ap = &lds[sa * SLOT + aRd];
        const u16* bp = &lds[sa * SLOT + bRd];
        s16x8 a[4], b[2][4];
        // ---------------- phase kk0 ----------------
#pragma unroll
        for (int mf = 0; mf < 4; mf++) a[mf] = *(const s16x8*)(ap + mf * 1024);
#pragma unroll
        for (int kk = 0; kk < 2; kk++)
#pragma unroll
            for (int nf = 0; nf < 4; nf++)
                b[kk][nf] = *(const s16x8*)(bp + nf * 1024 + kk * 32);
        STAGE_A(sc, ts, 0); STAGE_A(sc, ts, 1); STAGE_B(sc, ts, 0);
        SBAR();
        asm volatile("s_waitcnt lgkmcnt(0)" ::: "memory");
        __builtin_amdgcn_sched_barrier(0);
        __builtin_amdgcn_s_setprio(1);
#pragma unroll
        for (int nf = 0; nf < 4; nf++)
#pragma unroll
            for (int mf = 0; mf < 4; mf++)
                acc[mf][nf] = __builtin_amdgcn_mfma_f32_16x16x32_bf16(
                    a[mf], b[0][nf], acc[mf][nf], 0, 0, 0);
        __builtin_amdgcn_s_setprio(0);
        SBAR();
        // ---------------- phase kk1 ----------------
#pragma unroll
        for (int mf = 0; mf < 4; mf++)
            a[mf] = *(const s16x8*)(ap + mf * 1024 + 32);
        STAGE_B(sc, ts, 1); STAGE_B(sc, ts, 2); STAGE_B(sc, ts, 3);
        SBAR();
        asm volatile("s_waitcnt lgkmcnt(0)" ::: "memory");
        __builtin_amdgcn_sched_barrier(0);
        __builtin_amdgcn_s_setprio(1);
#pragma unroll
        for (int nf = 0; nf < 4; nf++)
#pragma unroll
            for (int mf = 0; mf < 4; mf++)
                acc[mf][nf] = __builtin_amdgcn_mfma_f32_16x16x32_bf16(
                    a[mf], b[1][nf], acc[mf][nf], 0, 0, 0);
        __builtin_amdgcn_s_setprio(0);
        asm volatile("s_waitcnt vmcnt(6)" ::: "memory");
        __builtin_amdgcn_sched_barrier(0);
        SBAR();
        int tmp = sa; sa = sb; sb = sc; sc = tmp;
    }
#undef STAGE_A
#undef STAGE_B

    if (f16out) {
        // XIT path: write f16 transposed [N][M] via LDS (stride 136 u16 keeps
        // b128 reads 16B-aligned). MUST drain in-flight global_load_lds DMAs
        // (up to 6 outstanding, targeting these LDS slots) before reuse.
        asm volatile("s_waitcnt vmcnt(0)" ::: "memory");
        __syncthreads();
        u16* tb = lds;
#pragma unroll
        for (int mf = 0; mf < 4; mf++)
#pragma unroll
            for (int nf = 0; nf < 4; nf++) {
                int c = cb * 64 + nf * 16 + l15;
                int r = rb * 64 + mf * 16 + quad * 4;
#pragma unroll
                for (int reg = 0; reg < 4; reg++)
                    tb[c * 136 + r + reg] = f2h(acc[mf][nf][reg]);
            }
        __syncthreads();
#pragma unroll
        for (int it = 0; it < 8; it++) {
            int c = (tid >> 4) + it * 32;
            int r0 = (tid & 15) * 8;
            uint4 v4 = *(const uint4*)&tb[c * 136 + r0];
            *(uint4*)&Cb[(size_t)(bn + c) * M + bm + r0] = v4;
        }
        return;
    }

    // epilogue (row-major)
#pragma unroll
    for (int mf = 0; mf < 4; mf++) {
        int row0 = bm + rb * 64 + mf * 16 + quad * 4;
#pragma unroll
        for (int nf = 0; nf < 4; nf++) {
            int col = bn + cb * 64 + nf * 16 + l15;
            // Q-scale with log2(e) folded: 0.125 * 1.4426950408889634
            float a2 = (col < qcols) ? alpha * 0.18033688011112042f : alpha;
            float bv = bias ? bias[col] : 0.f;
#pragma unroll
            for (int reg = 0; reg < 4; reg++) {
                float v = a2 * acc[mf][nf][reg] + bv;
                if (act) v = gelu_t(v);
                size_t idx = (size_t)(row0 + reg) * N + col;
                if (resid) v += resid[idx];
                if (C) C[idx] = v;
                else Cb[idx] = f2bf(v);
            }
        }
    }
}

// ---------------------------------------------------------------------------
// Causal per-channel conv: out[b,l,d] = sum_{t=0..l} F[t,d]*XI[b,l-t,d]
// Transposed f16 inputs, b128 staging, fdot2 ring kernel, XCD-group swizzle.
// v8: 2048 single-tile blocks (was 1024 paired): LDS 25.6KB allows 6
//     blocks/CU but the paired grid only provided 4 -- more co-resident
//     blocks is the TLP that covers the serial stage/barrier chain.
//     Longest-first order per XCD (lt = 31-(ix&31)) so the scheduler
//     backfills short blocks at the tail.
// ---------------------------------------------------------------------------
__global__ __launch_bounds__(256, 6) void conv_k(const u16* __restrict__ FT,
                                                 const u16* __restrict__ XT,
                                                 float* __restrict__ OUT) {
    int bid = blockIdx.x;
    int xcd = bid & 7, ix = bid >> 3;          // ix in [0,256)
    int group = xcd * 8 + (ix >> 5);           // 64 (d0,b) groups, 8 per XCD
    int lt = 31 - (ix & 31);                   // longest tile first
    int d0 = (group & 15) * 64, b = group >> 4;

    __shared__ u16 xs[64][132];
    __shared__ u16 ftr[64][68];
    int tid = threadIdx.x;
    int dd = tid & 63;
    int jg = tid >> 6;
    int L0 = jg * 16;
    int frow = tid >> 3, fq = (tid & 7) * 8;
    int xrow = tid >> 4, xq = (tid & 15) * 8;
    const u16* fbase = FT + (size_t)(d0 + frow) * L_ + fq;
    const u16* xbase = XT + (size_t)(d0 + xrow) * (B_ * L_) + (size_t)b * L_ + xq;

    int l0 = lt * 64;
    float acc[16];
#pragma unroll
    for (int i = 0; i < 16; i++) acc[i] = 0.f;

    for (int t0 = 0; t0 <= l0; t0 += 64) {
        int jb = l0 - t0 - 64;
#pragma unroll
        for (int p = 0; p < 2; p++) {
            uint4 Fq = *(const uint4*)(fbase + (size_t)p * 32 * L_ + t0);
            *(uint2*)&ftr[frow + p * 32][fq] = make_uint2(Fq.x, Fq.y);
            *(uint2*)&ftr[frow + p * 32][fq + 4] = make_uint2(Fq.z, Fq.w);
        }
        if (jb >= 0) {
#pragma unroll
            for (int p = 0; p < 4; p++) {
                uint4 Xq = *(const uint4*)(xbase + (size_t)p * 16 * (B_ * L_) + jb);
                *(uint2*)&xs[xrow + p * 16][xq] = make_uint2(Xq.x, Xq.y);
                *(uint2*)&xs[xrow + p * 16][xq + 4] = make_uint2(Xq.z, Xq.w);
            }
        } else {
#pragma unroll
            for (int p = 0; p < 4; p++) {
                uint4 Xq = make_uint4(0, 0, 0, 0);
                if (xq >= 64)
                    Xq = *(const uint4*)(xbase + (size_t)p * 16 * (B_ * L_) - 64);
                *(uint2*)&xs[xrow + p * 16][xq] = make_uint2(Xq.x, Xq.y);
                *(uint2*)&xs[xrow + p * 16][xq + 4] = make_uint2(Xq.z, Xq.w);
            }
        }
        __syncthreads();

        unsigned Q[10], E[10];
        {
            uint2 q0 = *(const uint2*)&xs[dd][L0];
            uint2 q1 = *(const uint2*)&xs[dd][L0 + 4];
            uint2 q2 = *(const uint2*)&xs[dd][L0 + 8];
            uint2 q3 = *(const uint2*)&xs[dd][L0 + 12];
            Q[0] = q0.x; Q[1] = q0.y; Q[2] = q1.x; Q[3] = q1.y;
            Q[4] = q2.x; Q[5] = q2.y; Q[6] = q3.x; Q[7] = q3.y;
#pragma unroll
            for (int j = 0; j < 7; j++)
                E[j] = __builtin_amdgcn_alignbit(Q[j + 1], Q[j], 16);
        }
#pragma unroll
        for (int s = 0; s < 16; s++) {
            const int h = (2 * s) % 10;
            uint2 nx = *(const uint2*)&xs[dd][L0 + 16 + 4 * s];
            Q[(h + 8) % 10] = nx.x;
            Q[(h + 9) % 10] = nx.y;
            E[(h + 7) % 10] = __builtin_amdgcn_alignbit(Q[(h + 8) % 10], Q[(h + 7) % 10], 16);
            E[(h + 8) % 10] = __builtin_amdgcn_alignbit(Q[(h + 9) % 10], Q[(h + 8) % 10], 16);
            uint2 fr = *(const uint2*)&ftr[dd][4 * s];
            h2 f01 = __builtin_bit_cast(h2, fr.x);
            h2 f23 = __builtin_bit_cast(h2, fr.y);
#pragma unroll
            for (int i = 0; i < 16; i += 2) {
                const int p = (h + i / 2) % 10;
                const int p1 = (h + i / 2 + 1) % 10;
                const int p2 = (h + i / 2 + 2) % 10;
                acc[i] = __builtin_amdgcn_fdot2(f01, __builtin_bit_cast(h2, E[p]), acc[i], false);
                acc[i] = __builtin_amdgcn_fdot2(f23, __builtin_bit_cast(h2, E[p1]), acc[i], false);
                acc[i + 1] = __builtin_amdgcn_fdot2(f01, __builtin_bit_cast(h2, Q[p1]), acc[i + 1], false);
                acc[i + 1] = __builtin_amdgcn_fdot2(f23, __builtin_bit_cast(h2, Q[p2]), acc[i + 1], false);
            }
        }
        __syncthreads();
    }
#pragma unroll
    for (int i = 0; i < 16; i++)
        OUT[((size_t)b * L_ + l0 + L0 + i) * D_ + d0 + dd] = acc[i];
}

// ---------------------------------------------------------------------------
// LayerNorm -> bf16 out (row = 1024), eps 1e-6
// ---------------------------------------------------------------------------
__global__ __launch_bounds__(256) void layernorm_bf16(const float* __restrict__ x,
                                                      const float* __restrict__ scale,
                                                      const float* __restrict__ bias,
                                                      u16* __restrict__ y) {
    size_t row = blockIdx.x;
    int tid = threadIdx.x;
    const float4 v = *(const float4*)&x[row * D_ + tid * 4];
    float s = v.x + v.y + v.z + v.w;
    float q = v.x * v.x + v.y * v.y + v.z * v.z + v.w * v.w;
#pragma unroll
    for (int off = 32; off >= 1; off >>= 1) {
        s += __shfl_xor(s, off, 64);
        q += __shfl_xor(q, off, 64);
    }
    __shared__ float ss[4], sq[4];
    int w = tid >> 6;
    if ((tid & 63) == 0) { ss[w] = s; sq[w] = q; }
    __syncthreads();
    s = ss[0] + ss[1] + ss[2] + ss[3];
    q = sq[0] + sq[1] + sq[2] + sq[3];
    float mean = s * (1.f / D_);
    float var = q * (1.f / D_) - mean * mean;
    float r = rsqrtf(var + 1e-6f);
    const float4 sc = *(const float4*)&scale[tid * 4];
    const float4 bi = *(const float4*)&bias[tid * 4];
    ushort4 o;
    o.x = f2bf((v.x - mean) * r * sc.x + bi.x);
    o.y = f2bf((v.y - mean) * r * sc.y + bi.y);
    o.z = f2bf((v.z - mean) * r * sc.z + bi.z);
    o.w = f2bf((v.w - mean) * r * sc.w + bi.w);
    *(ushort4*)&y[row * D_ + tid * 4] = o;
}

// ---------------------------------------------------------------------------
// MFMA flash attention, TQ=128. no-max softmax + K/V reg prefetch + XCD swz.
// Q pre-scaled by 0.125*log2e at the QKV GEMM -> P = v_exp_f32(score)
// directly (2^(s*log2e) = e^s exactly; softmax unchanged).
// cvt_pk_bf16_f32 P-store + setprio around MFMA clusters.
// ---------------------------------------------------------------------------
__global__ __launch_bounds__(256) void attn_mfma(const u16* __restrict__ Qg,
                                                 const u16* __restrict__ Kg,
                                                 const u16* __restrict__ Vg,
                                                 u16* __restrict__ Og) {
    const int QSTR = 3072;
    int bxs = blockIdx.x, bys = blockIdx.y;
    {
        int bid = blockIdx.x + gridDim.x * blockIdx.y;
        int xcd = bid & 7, idx = bid >> 3;
        bys = xcd + 8 * (idx / gridDim.x);
        bxs = idx % gridDim.x;
    }
    int q0 = bxs * 128;
    int b = bys >> 4, h = bys & 15;
    __shared__ __align__(16) u16 qs[128 * 72];
    __shared__ __align__(16) u16 ks[64 * 72];
    __shared__ __align__(16) u16 vt[64 * 72];   // V^T: [hd][s]
    int tid = threadIdx.x;
    int w = tid >> 6, lane = tid & 63;
    int quad = lane >> 4, l15 = lane & 15;
    const size_t base = (size_t)b * L_ * QSTR + h * HD_;

#pragma unroll
    for (int i = tid; i < 128 * 8; i += 256) {
        int r = i >> 3, c = i & 7;
        *(uint4*)&qs[r * 72 + c * 8] =
            *(const uint4*)&Qg[base + (size_t)(q0 + r) * QSTR + c * 8];
    }
    __syncthreads();
    s16x8 aq[2][2];
#pragma unroll
    for (int mi = 0; mi < 2; mi++)
#pragma unroll
        for (int kb = 0; kb < 2; kb++)
            aq[mi][kb] = *(const s16x8*)&qs[(w * 32 + mi * 16 + l15) * 72 + kb * 32 + quad * 8];

    float rsacc[2][4];
    fx4 o[2][4];
#pragma unroll
    for (int mi = 0; mi < 2; mi++)
#pragma unroll
        for (int i = 0; i < 4; i++) {
            rsacc[mi][i] = 0.f;
            o[mi][i] = (fx4){0.f, 0.f, 0.f, 0.f};
        }
    u16* psw = qs + w * 32 * 72;

    int kr0 = tid >> 3, kc = tid & 7;
    const u16* kg0 = Kg + base + (size_t)kr0 * QSTR + kc * 8;
    const u16* kg1 = kg0 + (size_t)32 * QSTR;
    const u16* vg = Vg + base + (size_t)lane * QSTR + w * 8;
    uint4 kp0 = *(const uint4*)kg0;
    uint4 kp1 = *(const uint4*)kg1;
    uint4 vp0 = *(const uint4*)vg;
    uint4 vp1 = *(const uint4*)(vg + 32);

    for (int s0 = 0; s0 < L_; s0 += 64) {
        __syncthreads();
        *(uint4*)&ks[kr0 * 72 + kc * 8] = kp0;
        *(uint4*)&ks[(kr0 + 32) * 72 + kc * 8] = kp1;
        {
            u16 t0[8], t1[8];
            *(uint4*)t0 = vp0;
            *(uint4*)t1 = vp1;
#pragma unroll
            for (int j = 0; j < 8; j++) vt[(w * 8 + j) * 72 + lane] = t0[j];
#pragma unroll
            for (int j = 0; j < 8; j++) vt[(w * 8 + 32 + j) * 72 + lane] = t1[j];
        }
        if (s0 + 64 < L_) {
            size_t off = (size_t)(s0 + 64) * QSTR;
            kp0 = *(const uint4*)(kg0 + off);
            kp1 = *(const uint4*)(kg1 + off);
            vp0 = *(const uint4*)(vg + off);
            vp1 = *(const uint4*)(vg + off + 32);
        }
        __syncthreads();

        fx4 sv[2][4];
#pragma unroll
        for (int mi = 0; mi < 2; mi++)
#pragma unroll
            for (int nt = 0; nt < 4; nt++) sv[mi][nt] = (fx4){0.f, 0.f, 0.f, 0.f};
        __builtin_amdgcn_s_setprio(1);
#pragma unroll
        for (int kb = 0; kb < 2; kb++)
#pragma unroll
            for (int nt = 0; nt < 4; nt++) {
                s16x8 bk = *(const s16x8*)&ks[(nt * 16 + l15) * 72 + kb * 32 + quad * 8];
#pragma unroll
                for (int mi = 0; mi < 2; mi++)
                    sv[mi][nt] = __builtin_amdgcn_mfma_f32_16x16x32_bf16(
                        aq[mi][kb], bk, sv[mi][nt], 0, 0, 0);
            }
        __builtin_amdgcn_s_setprio(0);

        // linear softmax accumulation; scores pre-scaled by log2e -> raw exp2
#pragma unroll
        for (int mi = 0; mi < 2; mi++)
#pragma unroll
            for (int nt = 0; nt < 4; nt++) {
                float p0 = exp2_hw(sv[mi][nt][0]);
                float p1 = exp2_hw(sv[mi][nt][1]);
                float p2 = exp2_hw(sv[mi][nt][2]);
                float p3 = exp2_hw(sv[mi][nt][3]);
                rsacc[mi][0] += p0; rsacc[mi][1] += p1;
                rsacc[mi][2] += p2; rsacc[mi][3] += p3;
                unsigned pk01, pk23;
                asm("v_cvt_pk_bf16_f32 %0, %1, %2" : "=v"(pk01) : "v"(p0), "v"(p1));
                asm("v_cvt_pk_bf16_f32 %0, %1, %2" : "=v"(pk23) : "v"(p2), "v"(p3));
                int basei = (mi * 16 + quad * 4) * 72 + nt * 16 + l15;
                psw[basei]       = (u16)pk01;
                psw[basei + 72]  = (u16)(pk01 >> 16);
                psw[basei + 144] = (u16)pk23;
                psw[basei + 216] = (u16)(pk23 >> 16);
            }

        __builtin_amdgcn_s_setprio(1);
#pragma unroll
        for (int kb = 0; kb < 2; kb++) {
            s16x8 ap[2];
#pragma unroll
            for (int mi = 0; mi < 2; mi++)
                ap[mi] = *(const s16x8*)&psw[(mi * 16 + l15) * 72 + kb * 32 + quad * 8];
#pragma unroll
            for (int nt = 0; nt < 4; nt++) {
                s16x8 bv = *(const s16x8*)&vt[(nt * 16 + l15) * 72 + kb * 32 + quad * 8];
#pragma unroll
                for (int mi = 0; mi < 2; mi++)
                    o[mi][nt] = __builtin_amdgcn_mfma_f32_16x16x32_bf16(
                        ap[mi], bv, o[mi][nt], 0, 0, 0);
            }
        }
        __builtin_amdgcn_s_setprio(0);
    }
    float lsum[2][4];
#pragma unroll
    for (int mi = 0; mi < 2; mi++)
#pragma unroll
        for (int reg = 0; reg < 4; reg++) {
            float r = rsacc[mi][reg];
#pragma unroll
            for (int off = 8; off >= 1; off >>= 1)
                r += __shfl_xor(r, off, 16);
            lsum[mi][reg] = r;
        }
    const size_t baseo = (size_t)b * L_ * 1024 + h * HD_;
#pragma unroll
    for (int mi = 0; mi < 2; mi++)
#pragma unroll
        for (int reg = 0; reg < 4; reg++) {
            float inv = 1.f / lsum[mi][reg];
            size_t row = baseo +
                (size_t)(q0 + w * 32 + mi * 16 + quad * 4 + reg) * 1024;
#pragma unroll
            for (int nt = 0; nt < 4; nt++)
                Og[row + nt * 16 + l15] = f2bf(o[mi][nt][reg] * inv);
        }
}

// ---------------------------------------------------------------------------
extern "C" void kernel_launch(void* const* d_in, const int* in_sizes, int n_in,
                              void* d_out, int out_size, void* d_ws, size_t ws_size,
                              hipStream_t stream) {
    const float* inputs   = (const float*)d_in[0];
    const float* eig_vals = (const float*)d_in[1];
    const float* eig_vecs = (const float*)d_in[2];
    const float* w_filt   = (const float*)d_in[3];
    const float* w_inp    = (const float*)d_in[4];
    const float* ln1_s    = (const float*)d_in[5];
    const float* ln1_b    = (const float*)d_in[6];
    const float* wq       = (const float*)d_in[7];
    const float* wk       = (const float*)d_in[8];
    const float* wv       = (const float*)d_in[9];
    const float* wo       = (const float*)d_in[10];
    const float* ln2_s    = (const float*)d_in[11];
    const float* ln2_b    = (const float*)d_in[12];
    const float* w1       = (const float*)d_in[13];
    const float* b1       = (const float*)d_in[14];
    const float* w2       = (const float*)d_in[15];
    const float* b2       = (const float*)d_in[16];
    float* out = (float*)d_out;
    char* ws = (char*)d_ws;
    const size_t MB = 1u << 20;
    u16*   INb   = (u16*)(ws + 0 * MB);
    u16*   WIt   = (u16*)(ws + 16 * MB);
    u16*   WQKVt = (u16*)(ws + 18 * MB);
    u16*   WOt   = (u16*)(ws + 24 * MB);
    u16*   W1t   = (u16*)(ws + 26 * MB);
    u16*   W2t   = (u16*)(ws + 34 * MB);
    u16*   HID   = (u16*)(ws + 48 * MB);
    u16*   XIT   = (u16*)(ws + 64 * MB);
    float* STU   = (float*)(ws + 80 * MB);
    u16*   XN    = (u16*)(ws + 112 * MB);
    u16*   QKV   = (u16*)(ws + 128 * MB);
    float* Xb    = (float*)(ws + 128 * MB);
    u16*   YN    = (u16*)(ws + 160 * MB);
    u16*   FvT   = (u16*)(ws + 176 * MB);
    u16*   Ab    = (u16*)(ws + 176 * MB);

    const int M = B_ * L_;

    cast_bf16<<<(M * D_ / 4 + 255) / 256, 256, 0, stream>>>(inputs, INb);

    // all 7 weight transposes in one launch
    CastJobs J;
    J.src[0] = w_inp; J.dst[0] = WIt;               J.R[0] = D_;   J.C[0] = D_;
    J.src[1] = wq;    J.dst[1] = WQKVt + 0 * D_ * D_; J.R[1] = D_; J.C[1] = D_;
    J.src[2] = wk;    J.dst[2] = WQKVt + 1 * D_ * D_; J.R[2] = D_; J.C[2] = D_;
    J.src[3] = wv;    J.dst[3] = WQKVt + 2 * D_ * D_; J.R[3] = D_; J.C[3] = D_;
    J.src[4] = wo;    J.dst[4] = WOt;               J.R[4] = D_;   J.C[4] = D_;
    J.src[5] = w1;    J.dst[5] = W1t;               J.R[5] = D_;   J.C[5] = MLP_;
    J.src[6] = w2;    J.dst[6] = W2t;               J.R[6] = MLP_; J.C[6] = D_;
    J.src[7] = w_inp; J.dst[7] = WIt;               J.R[7] = D_;   J.C[7] = D_;
    int nb = 0;
    for (int j = 0; j < 7; j++) {
        J.off[j] = nb;
        nb += (J.C[j] / 32) * (J.R[j] / 32);
    }
    J.off[7] = nb;   // sentinel: bid never reaches job 7
    cast_T_all<<<nb, 256, 0, stream>>>(J);

    filters_T<<<dim3(L_ / 64, D_ / 64), 256, 0, stream>>>(eig_vals, eig_vecs, w_filt, FvT);

    // XI = INb @ WIt^T -> written DIRECTLY transposed f16 [D][M] (XIT)
    gemm_bf16<<<dim3(D_ / 256, M / 128), 512, 0, stream>>>(
        INb, WIt, nullptr, XIT, M, D_, D_, 1.f, nullptr, nullptr, 0, 0, 1);
    conv_k<<<2048, 256, 0, stream>>>(FvT, XIT, STU);
    layernorm_bf16<<<M, 256, 0, stream>>>(STU, ln1_s, ln1_b, XN);
    // fused QKV (cols<1024 get the 0.125*log2e Q-scale)
    gemm_bf16<<<dim3(3 * D_ / 256, M / 128), 512, 0, stream>>>(
        XN, WQKVt, nullptr, QKV, M, 3 * D_, D_, 1.f, nullptr, nullptr, 0, D_, 0);
    attn_mfma<<<dim3(L_ / 128, B_ * H_), 256, 0, stream>>>(
        QKV, QKV + D_, QKV + 2 * D_, Ab);
    gemm_bf16<<<dim3(D_ / 256, M / 128), 512, 0, stream>>>(
        Ab, WOt, Xb, nullptr, M, D_, D_, 1.f, nullptr, STU, 0, 0, 0);
    layernorm_bf16<<<M, 256, 0, stream>>>(Xb, ln2_s, ln2_b, YN);
    gemm_bf16<<<dim3(MLP_ / 256, M / 128), 512, 0, stream>>>(
        YN, W1t, nullptr, HID, M, MLP_, D_, 1.f, b1, nullptr, 1, 0, 0);
    gemm_bf16<<<dim3(D_ / 256, M / 128), 512, 0, stream>>>(
        HID, W2t, out, nullptr, M, D_, MLP_, 1.f, b2, Xb, 0, 0, 0);
}

// Round 13
// 768.826 us; speedup vs baseline: 1.0948x; 1.0948x over previous
//
#include <hip/hip_runtime.h>
#include <math.h>

#define B_ 4
#define L_ 2048
#define D_ 1024
#define H_ 16
#define HD_ 64
#define K_ 24
#define MLP_ 4096

typedef unsigned short u16;
typedef short s16x8 __attribute__((ext_vector_type(8)));
typedef float fx4 __attribute__((ext_vector_type(4)));
typedef _Float16 h2 __attribute__((ext_vector_type(2)));

__device__ __forceinline__ u16 f2bf(float f) {
    unsigned u = __float_as_uint(f);
    unsigned r = (u + 0x7fff + ((u >> 16) & 1)) >> 16;
    return (u16)r;
}

__device__ __forceinline__ u16 f2h(float f) {
    _Float16 hv = (_Float16)f;
    return __builtin_bit_cast(u16, hv);
}

__device__ __forceinline__ float exp2_hw(float x) {
    float r;
    asm("v_exp_f32 %0, %1" : "=v"(r) : "v"(x));
    return r;
}

// tanh-approx GELU with the exp folded to base-2 (raw v_exp_f32, no guards)
__device__ __forceinline__ float gelu_t(float x) {
    float u = 0.7978845608028654f * (x + 0.044715f * x * x * x);
    return x / (1.f + exp2_hw(-2.8853900817779268f * u));
}

__device__ __forceinline__ void gload_lds16(const void* g, void* l) {
    __builtin_amdgcn_global_load_lds(
        (const __attribute__((address_space(1))) unsigned int*)g,
        (__attribute__((address_space(3))) unsigned int*)l, 16, 0, 0);
}

#define SBAR() do { __builtin_amdgcn_sched_barrier(0); \
                    __builtin_amdgcn_s_barrier(); \
                    __builtin_amdgcn_sched_barrier(0); } while (0)

// ---------------------------------------------------------------------------
// Spectral filters, computed directly transposed+reversed:
// FvT[d][l0 + (l&63)^63] = sum_k eig_vecs[l,k]*ev^0.25[k]*w_filters[k,d] (f16)
// ---------------------------------------------------------------------------
__global__ __launch_bounds__(256) void filters_T(const float* __restrict__ eig_vals,
                                                 const float* __restrict__ eig_vecs,
                                                 const float* __restrict__ w_filters,
                                                 u16* __restrict__ outT) {
    int l0 = blockIdx.x * 64, d0 = blockIdx.y * 64;
    __shared__ float ev25[K_];
    __shared__ float rr[64][25];
    __shared__ float wfs[K_][64];
    int tid = threadIdx.x;
    if (tid < K_) ev25[tid] = powf(eig_vals[tid], 0.25f);
    __syncthreads();
    for (int i = tid; i < 64 * K_; i += 256)
        rr[i / K_][i % K_] = eig_vecs[l0 * K_ + i];
    for (int i = tid; i < K_ * 64; i += 256) {
        int k = i >> 6, dd = i & 63;
        wfs[k][dd] = ev25[k] * w_filters[k * D_ + d0 + dd];
    }
    __syncthreads();
    int lane = tid & 63, w = tid >> 6;
    float acc[16];
#pragma unroll
    for (int i = 0; i < 16; i++) acc[i] = 0.f;
#pragma unroll
    for (int k = 0; k < K_; k++) {
        float rv = rr[lane][k];
#pragma unroll
        for (int i = 0; i < 16; i++) acc[i] += rv * wfs[k][w * 16 + i];
    }
#pragma unroll
    for (int i = 0; i < 16; i++)
        outT[(size_t)(d0 + w * 16 + i) * L_ + l0 + (lane ^ 63)] = f2h(acc[i]);
}

// ---------------------------------------------------------------------------
__global__ __launch_bounds__(256) void cast_bf16(const float* __restrict__ in,
                                                 u16* __restrict__ out) {
    int i = blockIdx.x * 256 + threadIdx.x;
    float4 v = ((const float4*)in)[i];
    ushort4 o;
    o.x = f2bf(v.x); o.y = f2bf(v.y); o.z = f2bf(v.z); o.w = f2bf(v.w);
    ((ushort4*)out)[i] = o;
}

// ---------------------------------------------------------------------------
// Batched fp32 [R][C] -> bf16 [C][R] transpose-cast: all weight transposes
// in ONE launch (job table by value; prefix-offset block mapping).
// ---------------------------------------------------------------------------
struct CastJobs {
    const float* src[8];
    u16* dst[8];
    int R[8], C[8];
    int off[8];   // block prefix offsets; off[j]..off[j+1) -> job j
};

__global__ __launch_bounds__(256) void cast_T_all(CastJobs J) {
    __shared__ float t[32][33];
    int bid = blockIdx.x;
    int j = 0;
#pragma unroll
    for (int k = 1; k < 8; k++)
        if (bid >= J.off[k]) j = k;
    int local = bid - J.off[j];
    int R = J.R[j], C = J.C[j];
    int nbx = C >> 5;                 // power of two (32 or 128)
    int lsh = __ffs(nbx) - 1;
    int bx = local & (nbx - 1), by = local >> lsh;
    const float* in = J.src[j];
    u16* out = J.dst[j];
    int c0 = bx * 32, r0 = by * 32;
    int tx = threadIdx.x & 31, ty = threadIdx.x >> 5;
#pragma unroll
    for (int p = 0; p < 4; p++)
        t[ty + p * 8][tx] = in[(size_t)(r0 + ty + p * 8) * C + c0 + tx];
    __syncthreads();
#pragma unroll
    for (int p = 0; p < 4; p++)
        out[(size_t)(c0 + ty + p * 8) * R + r0 + tx] = f2bf(t[tx][ty + p * 8]);
}

// ---------------------------------------------------------------------------
// bf16 MFMA GEMM, 8-phase schedule (T2+T3+T4+T5). Tile 128x256, BK=64,
// 512 threads = 8 waves, 3-slot LDS rotation, counted vmcnt(6), st_16x32
// swizzle (linear LDS dest + inv-swizzled global src + swizzled ds_read).
// 4 barriers/K-tile. qcols: columns < qcols get alpha*0.125*log2(e).
// f16out: write f16 TRANSPOSED [N][M] via post-loop LDS transpose.
// ---------------------------------------------------------------------------
__global__ __launch_bounds__(512, 2) void gemm_bf16(
    const u16* __restrict__ A, const u16* __restrict__ Bt,
    float* __restrict__ C, u16* __restrict__ Cb,
    int M, int N, int K, float alpha,
    const float* __restrict__ bias, const float* __restrict__ resid, int act,
    int qcols, int f16out) {
    __shared__ __align__(16) u16 lds[3 * 24576];   // 3 slots x 48KB
    const int SLOT = 24576;   // u16 per slot
    const int BOFF = 8192;    // B-tile offset within slot (u16)

    int tid = threadIdx.x;
    int wid = tid >> 6, lane = tid & 63;
    int quad = lane >> 4, l15 = lane & 15;
    int rb = wid >> 2, cb = wid & 3;

    int bxs = blockIdx.x, bys = blockIdx.y;
    if ((gridDim.y & 7) == 0) {
        int bid = blockIdx.x + gridDim.x * blockIdx.y;
        int xcd = bid & 7, idx = bid >> 3;
        bys = xcd + 8 * (idx / gridDim.x);
        bxs = idx % gridDim.x;
    }
    int bm = bys * 128, bn = bxs * 256;
    int nt = K >> 6;

    int qoffe = (quad * 8) ^ ((l15 & 4) ? 16 : 0);
    int aRd = (rb * 64 + l15) * 64 + qoffe;            // + mf*1024 + kk*32
    int bRd = BOFF + (cb * 64 + l15) * 64 + qoffe;     // + nf*1024 + kk*32

    int srow = wid * 8 + (lane >> 3);
    int scole = ((lane & 7) * 8) ^ ((lane & 32) ? 16 : 0);
    const u16* Ag = A + (size_t)(bm + srow) * K + scole;
    const u16* Bg = Bt + (size_t)(bn + srow) * K + scole;
    int ldst = wid * 512;

#define STAGE_A(s, t, c) gload_lds16(Ag + (size_t)(c) * 64 * K + (size_t)(t) * 64, \
                                     &lds[(s) * SLOT + (c) * 4096 + ldst])
#define STAGE_B(s, t, c) gload_lds16(Bg + (size_t)(c) * 64 * K + (size_t)(t) * 64, \
                                     &lds[(s) * SLOT + BOFF + (c) * 4096 + ldst])

    STAGE_A(0, 0, 0); STAGE_A(0, 0, 1);
    STAGE_B(0, 0, 0); STAGE_B(0, 0, 1); STAGE_B(0, 0, 2); STAGE_B(0, 0, 3);
    STAGE_A(1, 1, 0); STAGE_A(1, 1, 1);
    STAGE_B(1, 1, 0); STAGE_B(1, 1, 1); STAGE_B(1, 1, 2); STAGE_B(1, 1, 3);
    asm volatile("s_waitcnt vmcnt(6)" ::: "memory");
    SBAR();

    fx4 acc[4][4];
#pragma unroll
    for (int i = 0; i < 4; i++)
#pragma unroll
        for (int j = 0; j < 4; j++) acc[i][j] = (fx4){0.f, 0.f, 0.f, 0.f};

    int sa = 0, sb = 1, sc = 2;
    for (int t = 0; t < nt; t++) {
        int ts = (t + 2 < nt) ? t + 2 : nt - 1;
        const u16* ap = &lds[sa * SLOT + aRd];
        const u16* bp = &lds[sa * SLOT + bRd];
        s16x8 a[4], b[2][4];
        // ---------------- phase kk0 ----------------
#pragma unroll
        for (int mf = 0; mf < 4; mf++) a[mf] = *(const s16x8*)(ap + mf * 1024);
#pragma unroll
        for (int kk = 0; kk < 2; kk++)
#pragma unroll
            for (int nf = 0; nf < 4; nf++)
                b[kk][nf] = *(const s16x8*)(bp + nf * 1024 + kk * 32);
        STAGE_A(sc, ts, 0); STAGE_A(sc, ts, 1); STAGE_B(sc, ts, 0);
        SBAR();
        asm volatile("s_waitcnt lgkmcnt(0)" ::: "memory");
        __builtin_amdgcn_sched_barrier(0);
        __builtin_amdgcn_s_setprio(1);
#pragma unroll
        for (int nf = 0; nf < 4; nf++)
#pragma unroll
            for (int mf = 0; mf < 4; mf++)
                acc[mf][nf] = __builtin_amdgcn_mfma_f32_16x16x32_bf16(
                    a[mf], b[0][nf], acc[mf][nf], 0, 0, 0);
        __builtin_amdgcn_s_setprio(0);
        SBAR();
        // ---------------- phase kk1 ----------------
#pragma unroll
        for (int mf = 0; mf < 4; mf++)
            a[mf] = *(const s16x8*)(ap + mf * 1024 + 32);
        STAGE_B(sc, ts, 1); STAGE_B(sc, ts, 2); STAGE_B(sc, ts, 3);
        SBAR();
        asm volatile("s_waitcnt lgkmcnt(0)" ::: "memory");
        __builtin_amdgcn_sched_barrier(0);
        __builtin_amdgcn_s_setprio(1);
#pragma unroll
        for (int nf = 0; nf < 4; nf++)
#pragma unroll
            for (int mf = 0; mf < 4; mf++)
                acc[mf][nf] = __builtin_amdgcn_mfma_f32_16x16x32_bf16(
                    a[mf], b[1][nf], acc[mf][nf], 0, 0, 0);
        __builtin_amdgcn_s_setprio(0);
        asm volatile("s_waitcnt vmcnt(6)" ::: "memory");
        __builtin_amdgcn_sched_barrier(0);
        SBAR();
        int tmp = sa; sa = sb; sb = sc; sc = tmp;
    }
#undef STAGE_A
#undef STAGE_B

    if (f16out) {
        // XIT path: write f16 transposed [N][M] via LDS (stride 136 u16 keeps
        // b128 reads 16B-aligned). MUST drain in-flight global_load_lds DMAs
        // (up to 6 outstanding, targeting these LDS slots) before reuse.
        asm volatile("s_waitcnt vmcnt(0)" ::: "memory");
        __syncthreads();
        u16* tb = lds;
#pragma unroll
        for (int mf = 0; mf < 4; mf++)
#pragma unroll
            for (int nf = 0; nf < 4; nf++) {
                int c = cb * 64 + nf * 16 + l15;
                int r = rb * 64 + mf * 16 + quad * 4;
#pragma unroll
                for (int reg = 0; reg < 4; reg++)
                    tb[c * 136 + r + reg] = f2h(acc[mf][nf][reg]);
            }
        __syncthreads();
#pragma unroll
        for (int it = 0; it < 8; it++) {
            int c = (tid >> 4) + it * 32;
            int r0 = (tid & 15) * 8;
            uint4 v4 = *(const uint4*)&tb[c * 136 + r0];
            *(uint4*)&Cb[(size_t)(bn + c) * M + bm + r0] = v4;
        }
        return;
    }

    // epilogue (row-major)
#pragma unroll
    for (int mf = 0; mf < 4; mf++) {
        int row0 = bm + rb * 64 + mf * 16 + quad * 4;
#pragma unroll
        for (int nf = 0; nf < 4; nf++) {
            int col = bn + cb * 64 + nf * 16 + l15;
            // Q-scale with log2(e) folded: 0.125 * 1.4426950408889634
            float a2 = (col < qcols) ? alpha * 0.18033688011112042f : alpha;
            float bv = bias ? bias[col] : 0.f;
#pragma unroll
            for (int reg = 0; reg < 4; reg++) {
                float v = a2 * acc[mf][nf][reg] + bv;
                if (act) v = gelu_t(v);
                size_t idx = (size_t)(row0 + reg) * N + col;
                if (resid) v += resid[idx];
                if (C) C[idx] = v;
                else Cb[idx] = f2bf(v);
            }
        }
    }
}

// ---------------------------------------------------------------------------
// Causal per-channel conv: out[b,l,d] = sum_{t=0..l} F[t,d]*XI[b,l-t,d]
// Balanced pairing (tiles i & 31-i, 33 equal steps/block) -- FINAL structure:
// single-tile split (r12) regressed from tail imbalance; prefetch regressed
// twice (TLP already covers latency). Transposed f16 inputs, b128 staging,
// fdot2 ring kernel, XCD-group swizzle.
// ---------------------------------------------------------------------------
__global__ __launch_bounds__(256, 6) void conv_k(const u16* __restrict__ FT,
                                                 const u16* __restrict__ XT,
                                                 float* __restrict__ OUT) {
    int bid = blockIdx.x + 16 * (blockIdx.y + 16 * blockIdx.z);
    int xcd = bid & 7, ix = bid >> 3;
    int group = xcd * 8 + (ix >> 4);
    int xblk = ix & 15;
    int d0 = (group & 15) * 64, b = group >> 4;

    __shared__ u16 xs[64][132];
    __shared__ u16 ftr[64][68];
    int tid = threadIdx.x;
    int dd = tid & 63;
    int jg = tid >> 6;
    int L0 = jg * 16;
    int frow = tid >> 3, fq = (tid & 7) * 8;
    int xrow = tid >> 4, xq = (tid & 15) * 8;
    const u16* fbase = FT + (size_t)(d0 + frow) * L_ + fq;
    const u16* xbase = XT + (size_t)(d0 + xrow) * (B_ * L_) + (size_t)b * L_ + xq;

#pragma unroll 1
    for (int half = 0; half < 2; half++) {
        int lt = half ? (31 - xblk) : xblk;
        int l0 = lt * 64;
        float acc[16];
#pragma unroll
        for (int i = 0; i < 16; i++) acc[i] = 0.f;

        for (int t0 = 0; t0 <= l0; t0 += 64) {
            int jb = l0 - t0 - 64;
#pragma unroll
            for (int p = 0; p < 2; p++) {
                uint4 Fq = *(const uint4*)(fbase + (size_t)p * 32 * L_ + t0);
                *(uint2*)&ftr[frow + p * 32][fq] = make_uint2(Fq.x, Fq.y);
                *(uint2*)&ftr[frow + p * 32][fq + 4] = make_uint2(Fq.z, Fq.w);
            }
            if (jb >= 0) {
#pragma unroll
                for (int p = 0; p < 4; p++) {
                    uint4 Xq = *(const uint4*)(xbase + (size_t)p * 16 * (B_ * L_) + jb);
                    *(uint2*)&xs[xrow + p * 16][xq] = make_uint2(Xq.x, Xq.y);
                    *(uint2*)&xs[xrow + p * 16][xq + 4] = make_uint2(Xq.z, Xq.w);
                }
            } else {
#pragma unroll
                for (int p = 0; p < 4; p++) {
                    uint4 Xq = make_uint4(0, 0, 0, 0);
                    if (xq >= 64)
                        Xq = *(const uint4*)(xbase + (size_t)p * 16 * (B_ * L_) - 64);
                    *(uint2*)&xs[xrow + p * 16][xq] = make_uint2(Xq.x, Xq.y);
                    *(uint2*)&xs[xrow + p * 16][xq + 4] = make_uint2(Xq.z, Xq.w);
                }
            }
            __syncthreads();

            unsigned Q[10], E[10];
            {
                uint2 q0 = *(const uint2*)&xs[dd][L0];
                uint2 q1 = *(const uint2*)&xs[dd][L0 + 4];
                uint2 q2 = *(const uint2*)&xs[dd][L0 + 8];
                uint2 q3 = *(const uint2*)&xs[dd][L0 + 12];
                Q[0] = q0.x; Q[1] = q0.y; Q[2] = q1.x; Q[3] = q1.y;
                Q[4] = q2.x; Q[5] = q2.y; Q[6] = q3.x; Q[7] = q3.y;
#pragma unroll
                for (int j = 0; j < 7; j++)
                    E[j] = __builtin_amdgcn_alignbit(Q[j + 1], Q[j], 16);
            }
#pragma unroll
            for (int s = 0; s < 16; s++) {
                const int h = (2 * s) % 10;
                uint2 nx = *(const uint2*)&xs[dd][L0 + 16 + 4 * s];
                Q[(h + 8) % 10] = nx.x;
                Q[(h + 9) % 10] = nx.y;
                E[(h + 7) % 10] = __builtin_amdgcn_alignbit(Q[(h + 8) % 10], Q[(h + 7) % 10], 16);
                E[(h + 8) % 10] = __builtin_amdgcn_alignbit(Q[(h + 9) % 10], Q[(h + 8) % 10], 16);
                uint2 fr = *(const uint2*)&ftr[dd][4 * s];
                h2 f01 = __builtin_bit_cast(h2, fr.x);
                h2 f23 = __builtin_bit_cast(h2, fr.y);
#pragma unroll
                for (int i = 0; i < 16; i += 2) {
                    const int p = (h + i / 2) % 10;
                    const int p1 = (h + i / 2 + 1) % 10;
                    const int p2 = (h + i / 2 + 2) % 10;
                    acc[i] = __builtin_amdgcn_fdot2(f01, __builtin_bit_cast(h2, E[p]), acc[i], false);
                    acc[i] = __builtin_amdgcn_fdot2(f23, __builtin_bit_cast(h2, E[p1]), acc[i], false);
                    acc[i + 1] = __builtin_amdgcn_fdot2(f01, __builtin_bit_cast(h2, Q[p1]), acc[i + 1], false);
                    acc[i + 1] = __builtin_amdgcn_fdot2(f23, __builtin_bit_cast(h2, Q[p2]), acc[i + 1], false);
                }
            }
            __syncthreads();
        }
#pragma unroll
        for (int i = 0; i < 16; i++)
            OUT[((size_t)b * L_ + l0 + L0 + i) * D_ + d0 + dd] = acc[i];
    }
}

// ---------------------------------------------------------------------------
// LayerNorm -> bf16 out (row = 1024), eps 1e-6
// ---------------------------------------------------------------------------
__global__ __launch_bounds__(256) void layernorm_bf16(const float* __restrict__ x,
                                                      const float* __restrict__ scale,
                                                      const float* __restrict__ bias,
                                                      u16* __restrict__ y) {
    size_t row = blockIdx.x;
    int tid = threadIdx.x;
    const float4 v = *(const float4*)&x[row * D_ + tid * 4];
    float s = v.x + v.y + v.z + v.w;
    float q = v.x * v.x + v.y * v.y + v.z * v.z + v.w * v.w;
#pragma unroll
    for (int off = 32; off >= 1; off >>= 1) {
        s += __shfl_xor(s, off, 64);
        q += __shfl_xor(q, off, 64);
    }
    __shared__ float ss[4], sq[4];
    int w = tid >> 6;
    if ((tid & 63) == 0) { ss[w] = s; sq[w] = q; }
    __syncthreads();
    s = ss[0] + ss[1] + ss[2] + ss[3];
    q = sq[0] + sq[1] + sq[2] + sq[3];
    float mean = s * (1.f / D_);
    float var = q * (1.f / D_) - mean * mean;
    float r = rsqrtf(var + 1e-6f);
    const float4 sc = *(const float4*)&scale[tid * 4];
    const float4 bi = *(const float4*)&bias[tid * 4];
    ushort4 o;
    o.x = f2bf((v.x - mean) * r * sc.x + bi.x);
    o.y = f2bf((v.y - mean) * r * sc.y + bi.y);
    o.z = f2bf((v.z - mean) * r * sc.z + bi.z);
    o.w = f2bf((v.w - mean) * r * sc.w + bi.w);
    *(ushort4*)&y[row * D_ + tid * 4] = o;
}

// ---------------------------------------------------------------------------
// MFMA flash attention, TQ=128. no-max softmax + K/V reg prefetch + XCD swz.
// Q pre-scaled by 0.125*log2e at the QKV GEMM -> P = v_exp_f32(score)
// directly (2^(s*log2e) = e^s exactly; softmax unchanged).
// cvt_pk_bf16_f32 P-store + setprio around MFMA clusters.
// ---------------------------------------------------------------------------
__global__ __launch_bounds__(256) void attn_mfma(const u16* __restrict__ Qg,
                                                 const u16* __restrict__ Kg,
                                                 const u16* __restrict__ Vg,
                                                 u16* __restrict__ Og) {
    const int QSTR = 3072;
    int bxs = blockIdx.x, bys = blockIdx.y;
    {
        int bid = blockIdx.x + gridDim.x * blockIdx.y;
        int xcd = bid & 7, idx = bid >> 3;
        bys = xcd + 8 * (idx / gridDim.x);
        bxs = idx % gridDim.x;
    }
    int q0 = bxs * 128;
    int b = bys >> 4, h = bys & 15;
    __shared__ __align__(16) u16 qs[128 * 72];
    __shared__ __align__(16) u16 ks[64 * 72];
    __shared__ __align__(16) u16 vt[64 * 72];   // V^T: [hd][s]
    int tid = threadIdx.x;
    int w = tid >> 6, lane = tid & 63;
    int quad = lane >> 4, l15 = lane & 15;
    const size_t base = (size_t)b * L_ * QSTR + h * HD_;

#pragma unroll
    for (int i = tid; i < 128 * 8; i += 256) {
        int r = i >> 3, c = i & 7;
        *(uint4*)&qs[r * 72 + c * 8] =
            *(const uint4*)&Qg[base + (size_t)(q0 + r) * QSTR + c * 8];
    }
    __syncthreads();
    s16x8 aq[2][2];
#pragma unroll
    for (int mi = 0; mi < 2; mi++)
#pragma unroll
        for (int kb = 0; kb < 2; kb++)
            aq[mi][kb] = *(const s16x8*)&qs[(w * 32 + mi * 16 + l15) * 72 + kb * 32 + quad * 8];

    float rsacc[2][4];
    fx4 o[2][4];
#pragma unroll
    for (int mi = 0; mi < 2; mi++)
#pragma unroll
        for (int i = 0; i < 4; i++) {
            rsacc[mi][i] = 0.f;
            o[mi][i] = (fx4){0.f, 0.f, 0.f, 0.f};
        }
    u16* psw = qs + w * 32 * 72;

    int kr0 = tid >> 3, kc = tid & 7;
    const u16* kg0 = Kg + base + (size_t)kr0 * QSTR + kc * 8;
    const u16* kg1 = kg0 + (size_t)32 * QSTR;
    const u16* vg = Vg + base + (size_t)lane * QSTR + w * 8;
    uint4 kp0 = *(const uint4*)kg0;
    uint4 kp1 = *(const uint4*)kg1;
    uint4 vp0 = *(const uint4*)vg;
    uint4 vp1 = *(const uint4*)(vg + 32);

    for (int s0 = 0; s0 < L_; s0 += 64) {
        __syncthreads();
        *(uint4*)&ks[kr0 * 72 + kc * 8] = kp0;
        *(uint4*)&ks[(kr0 + 32) * 72 + kc * 8] = kp1;
        {
            u16 t0[8], t1[8];
            *(uint4*)t0 = vp0;
            *(uint4*)t1 = vp1;
#pragma unroll
            for (int j = 0; j < 8; j++) vt[(w * 8 + j) * 72 + lane] = t0[j];
#pragma unroll
            for (int j = 0; j < 8; j++) vt[(w * 8 + 32 + j) * 72 + lane] = t1[j];
        }
        if (s0 + 64 < L_) {
            size_t off = (size_t)(s0 + 64) * QSTR;
            kp0 = *(const uint4*)(kg0 + off);
            kp1 = *(const uint4*)(kg1 + off);
            vp0 = *(const uint4*)(vg + off);
            vp1 = *(const uint4*)(vg + off + 32);
        }
        __syncthreads();

        fx4 sv[2][4];
#pragma unroll
        for (int mi = 0; mi < 2; mi++)
#pragma unroll
            for (int nt = 0; nt < 4; nt++) sv[mi][nt] = (fx4){0.f, 0.f, 0.f, 0.f};
        __builtin_amdgcn_s_setprio(1);
#pragma unroll
        for (int kb = 0; kb < 2; kb++)
#pragma unroll
            for (int nt = 0; nt < 4; nt++) {
                s16x8 bk = *(const s16x8*)&ks[(nt * 16 + l15) * 72 + kb * 32 + quad * 8];
#pragma unroll
                for (int mi = 0; mi < 2; mi++)
                    sv[mi][nt] = __builtin_amdgcn_mfma_f32_16x16x32_bf16(
                        aq[mi][kb], bk, sv[mi][nt], 0, 0, 0);
            }
        __builtin_amdgcn_s_setprio(0);

        // linear softmax accumulation; scores pre-scaled by log2e -> raw exp2
#pragma unroll
        for (int mi = 0; mi < 2; mi++)
#pragma unroll
            for (int nt = 0; nt < 4; nt++) {
                float p0 = exp2_hw(sv[mi][nt][0]);
                float p1 = exp2_hw(sv[mi][nt][1]);
                float p2 = exp2_hw(sv[mi][nt][2]);
                float p3 = exp2_hw(sv[mi][nt][3]);
                rsacc[mi][0] += p0; rsacc[mi][1] += p1;
                rsacc[mi][2] += p2; rsacc[mi][3] += p3;
                unsigned pk01, pk23;
                asm("v_cvt_pk_bf16_f32 %0, %1, %2" : "=v"(pk01) : "v"(p0), "v"(p1));
                asm("v_cvt_pk_bf16_f32 %0, %1, %2" : "=v"(pk23) : "v"(p2), "v"(p3));
                int basei = (mi * 16 + quad * 4) * 72 + nt * 16 + l15;
                psw[basei]       = (u16)pk01;
                psw[basei + 72]  = (u16)(pk01 >> 16);
                psw[basei + 144] = (u16)pk23;
                psw[basei + 216] = (u16)(pk23 >> 16);
            }

        __builtin_amdgcn_s_setprio(1);
#pragma unroll
        for (int kb = 0; kb < 2; kb++) {
            s16x8 ap[2];
#pragma unroll
            for (int mi = 0; mi < 2; mi++)
                ap[mi] = *(const s16x8*)&psw[(mi * 16 + l15) * 72 + kb * 32 + quad * 8];
#pragma unroll
            for (int nt = 0; nt < 4; nt++) {
                s16x8 bv = *(const s16x8*)&vt[(nt * 16 + l15) * 72 + kb * 32 + quad * 8];
#pragma unroll
                for (int mi = 0; mi < 2; mi++)
                    o[mi][nt] = __builtin_amdgcn_mfma_f32_16x16x32_bf16(
                        ap[mi], bv, o[mi][nt], 0, 0, 0);
            }
        }
        __builtin_amdgcn_s_setprio(0);
    }
    float lsum[2][4];
#pragma unroll
    for (int mi = 0; mi < 2; mi++)
#pragma unroll
        for (int reg = 0; reg < 4; reg++) {
            float r = rsacc[mi][reg];
#pragma unroll
            for (int off = 8; off >= 1; off >>= 1)
                r += __shfl_xor(r, off, 16);
            lsum[mi][reg] = r;
        }
    const size_t baseo = (size_t)b * L_ * 1024 + h * HD_;
#pragma unroll
    for (int mi = 0; mi < 2; mi++)
#pragma unroll
        for (int reg = 0; reg < 4; reg++) {
            float inv = 1.f / lsum[mi][reg];
            size_t row = baseo +
                (size_t)(q0 + w * 32 + mi * 16 + quad * 4 + reg) * 1024;
#pragma unroll
            for (int nt = 0; nt < 4; nt++)
                Og[row + nt * 16 + l15] = f2bf(o[mi][nt][reg] * inv);
        }
}

// ---------------------------------------------------------------------------
extern "C" void kernel_launch(void* const* d_in, const int* in_sizes, int n_in,
                              void* d_out, int out_size, void* d_ws, size_t ws_size,
                              hipStream_t stream) {
    const float* inputs   = (const float*)d_in[0];
    const float* eig_vals = (const float*)d_in[1];
    const float* eig_vecs = (const float*)d_in[2];
    const float* w_filt   = (const float*)d_in[3];
    const float* w_inp    = (const float*)d_in[4];
    const float* ln1_s    = (const float*)d_in[5];
    const float* ln1_b    = (const float*)d_in[6];
    const float* wq       = (const float*)d_in[7];
    const float* wk       = (const float*)d_in[8];
    const float* wv       = (const float*)d_in[9];
    const float* wo       = (const float*)d_in[10];
    const float* ln2_s    = (const float*)d_in[11];
    const float* ln2_b    = (const float*)d_in[12];
    const float* w1       = (const float*)d_in[13];
    const float* b1       = (const float*)d_in[14];
    const float* w2       = (const float*)d_in[15];
    const float* b2       = (const float*)d_in[16];
    float* out = (float*)d_out;
    char* ws = (char*)d_ws;
    const size_t MB = 1u << 20;
    u16*   INb   = (u16*)(ws + 0 * MB);
    u16*   WIt   = (u16*)(ws + 16 * MB);
    u16*   WQKVt = (u16*)(ws + 18 * MB);
    u16*   WOt   = (u16*)(ws + 24 * MB);
    u16*   W1t   = (u16*)(ws + 26 * MB);
    u16*   W2t   = (u16*)(ws + 34 * MB);
    u16*   HID   = (u16*)(ws + 48 * MB);
    u16*   XIT   = (u16*)(ws + 64 * MB);
    float* STU   = (float*)(ws + 80 * MB);
    u16*   XN    = (u16*)(ws + 112 * MB);
    u16*   QKV   = (u16*)(ws + 128 * MB);
    float* Xb    = (float*)(ws + 128 * MB);
    u16*   YN    = (u16*)(ws + 160 * MB);
    u16*   FvT   = (u16*)(ws + 176 * MB);
    u16*   Ab    = (u16*)(ws + 176 * MB);

    const int M = B_ * L_;

    cast_bf16<<<(M * D_ / 4 + 255) / 256, 256, 0, stream>>>(inputs, INb);

    // all 7 weight transposes in one launch
    CastJobs J;
    J.src[0] = w_inp; J.dst[0] = WIt;               J.R[0] = D_;   J.C[0] = D_;
    J.src[1] = wq;    J.dst[1] = WQKVt + 0 * D_ * D_; J.R[1] = D_; J.C[1] = D_;
    J.src[2] = wk;    J.dst[2] = WQKVt + 1 * D_ * D_; J.R[2] = D_; J.C[2] = D_;
    J.src[3] = wv;    J.dst[3] = WQKVt + 2 * D_ * D_; J.R[3] = D_; J.C[3] = D_;
    J.src[4] = wo;    J.dst[4] = WOt;               J.R[4] = D_;   J.C[4] = D_;
    J.src[5] = w1;    J.dst[5] = W1t;               J.R[5] = D_;   J.C[5] = MLP_;
    J.src[6] = w2;    J.dst[6] = W2t;               J.R[6] = MLP_; J.C[6] = D_;
    J.src[7] = w_inp; J.dst[7] = WIt;               J.R[7] = D_;   J.C[7] = D_;
    int nb = 0;
    for (int j = 0; j < 7; j++) {
        J.off[j] = nb;
        nb += (J.C[j] / 32) * (J.R[j] / 32);
    }
    J.off[7] = nb;   // sentinel: bid never reaches job 7
    cast_T_all<<<nb, 256, 0, stream>>>(J);

    filters_T<<<dim3(L_ / 64, D_ / 64), 256, 0, stream>>>(eig_vals, eig_vecs, w_filt, FvT);

    // XI = INb @ WIt^T -> written DIRECTLY transposed f16 [D][M] (XIT)
    gemm_bf16<<<dim3(D_ / 256, M / 128), 512, 0, stream>>>(
        INb, WIt, nullptr, XIT, M, D_, D_, 1.f, nullptr, nullptr, 0, 0, 1);
    conv_k<<<dim3(16, D_ / 64, B_), 256, 0, stream>>>(FvT, XIT, STU);
    layernorm_bf16<<<M, 256, 0, stream>>>(STU, ln1_s, ln1_b, XN);
    // fused QKV (cols<1024 get the 0.125*log2e Q-scale)
    gemm_bf16<<<dim3(3 * D_ / 256, M / 128), 512, 0, stream>>>(
        XN, WQKVt, nullptr, QKV, M, 3 * D_, D_, 1.f, nullptr, nullptr, 0, D_, 0);
    attn_mfma<<<dim3(L_ / 128, B_ * H_), 256, 0, stream>>>(
        QKV, QKV + D_, QKV + 2 * D_, Ab);
    gemm_bf16<<<dim3(D_ / 256, M / 128), 512, 0, stream>>>(
        Ab, WOt, Xb, nullptr, M, D_, D_, 1.f, nullptr, STU, 0, 0, 0);
    layernorm_bf16<<<M, 256, 0, stream>>>(Xb, ln2_s, ln2_b, YN);
    gemm_bf16<<<dim3(MLP_ / 256, M / 128), 512, 0, stream>>>(
        YN, W1t, nullptr, HID, M, MLP_, D_, 1.f, b1, nullptr, 1, 0, 0);
    gemm_bf16<<<dim3(D_ / 256, M / 128), 512, 0, stream>>>(
        HID, W2t, out, nullptr, M, D_, MLP_, 1.f, b2, Xb, 0, 0, 0);
}